// Round 2
// baseline (816.704 us; speedup 1.0000x reference)
//
#include <hip/hip_runtime.h>

#define HW 65536
#define CH 64
#define NPIXF 4194304.0f
#define NBLK 1024

typedef __attribute__((ext_vector_type(8))) short short8;
typedef __attribute__((ext_vector_type(4))) short short4v;
typedef __attribute__((ext_vector_type(8))) __bf16 bf16x8;
typedef __attribute__((ext_vector_type(4))) float f32x4;

__device__ __forceinline__ unsigned short f2bf(float f) {
  unsigned int u = __builtin_bit_cast(unsigned int, f);
  u += 0x7FFFu + ((u >> 16) & 1u);
  return (unsigned short)(u >> 16);
}
__device__ __forceinline__ float bf2f(unsigned short h) {
  return __builtin_bit_cast(float, ((unsigned int)h) << 16);
}
__device__ __forceinline__ int swz(int p, int cc) { return cc ^ ((p ^ (p >> 3)) & 7); }

// ws byte layout:
//   0: cnt(u32)  4: gen(u32)
//   64:  sum_x[16] f32   (wsf idx 16..31)
//   128: sumsq_x[16]     (wsf idx 32..47)
//   192: sum_h[16]       (wsf idx 48..63)
//   256: sumsq_h[16]     (wsf idx 64..79)
//   512: u1[64]  (wsf 128..191)   768: v1[64] (wsf 192..255)
//   1024: u2[16] (wsf 256..271)   1088: v2[16] (wsf 272..287)
//   2048: a1 bf16[64][64]   10240: a2 bf16[16][64]   16384: t bf16[16][HW][64]
// first 512 B zeroed by hipMemsetAsync every launch.

__device__ __forceinline__ void gsync(unsigned* cnt, unsigned* gen, unsigned target) {
  __syncthreads();
  if (threadIdx.x == 0) {
    __threadfence();  // make this block's global writes visible device-wide
    unsigned old = __hip_atomic_fetch_add(cnt, 1u, __ATOMIC_ACQ_REL, __HIP_MEMORY_SCOPE_AGENT);
    if (old == (unsigned)NBLK - 1u) {
      __hip_atomic_store(cnt, 0u, __ATOMIC_RELAXED, __HIP_MEMORY_SCOPE_AGENT);
      __hip_atomic_fetch_add(gen, 1u, __ATOMIC_RELEASE, __HIP_MEMORY_SCOPE_AGENT);
    } else {
      unsigned spins = 0;
      while (__hip_atomic_load(gen, __ATOMIC_ACQUIRE, __HIP_MEMORY_SCOPE_AGENT) < target) {
        if (++spins > (1u << 27)) break;  // escape hatch: fail bounded, never hang
        __builtin_amdgcn_s_sleep(16);
      }
    }
    __threadfence();  // acquire side: invalidate caches before reading others' data
  }
  __syncthreads();
}

__global__ __launch_bounds__(256, 4) void fused(
    const float* __restrict__ x,
    const float* __restrict__ s1, const float* __restrict__ gb1,
    const float* __restrict__ w1, const float* __restrict__ b1,
    const float* __restrict__ s2, const float* __restrict__ gb2,
    const float* __restrict__ w2, const float* __restrict__ b2,
    unsigned char* __restrict__ ws, float* __restrict__ out) {
  unsigned* cnt = (unsigned*)ws;
  unsigned* gen = (unsigned*)(ws + 4);
  float* wsf = (float*)ws;
  unsigned short* a1 = (unsigned short*)(ws + 2048);
  unsigned short* a2 = (unsigned short*)(ws + 10240);
  unsigned short* t  = (unsigned short*)(ws + 16384);

  const int tid = threadIdx.x;
  const int l = tid & 63, w = tid >> 6;
  const int bid = blockIdx.x;
  const int s = bid >> 6;   // sample: 64 blocks per sample
  const int j = bid & 63;

  __shared__ __align__(16) unsigned char tile[128 * 128];
  __shared__ float red[8];
  __shared__ float c1s[64];
  __shared__ float c2s[8];

  // ---------- phase 0: weight prep (blocks 0..79, wave 0 only) ----------
  if (bid < 64 && w == 0) {
    int o = bid;
    float wv = w1[o * 64 + l];
    float wsc = wv * s1[l];
    a1[o * 64 + l] = f2bf(wsc);
    float u = wsc, vv = wv * gb1[l];
#pragma unroll
    for (int off = 32; off > 0; off >>= 1) {
      u += __shfl_down(u, off, 64);
      vv += __shfl_down(vv, off, 64);
    }
    if (l == 0) { wsf[128 + o] = u; wsf[192 + o] = b1[o] + vv; }
  } else if (bid >= 64 && bid < 80 && w == 0) {
    int o = bid - 64;
    float wv = (o < 6) ? w2[o * 64 + l] : 0.f;
    float wsc = wv * s2[l];
    a2[o * 64 + l] = f2bf(wsc);
    float u = wsc, vv = wv * gb2[l];
#pragma unroll
    for (int off = 32; off > 0; off >>= 1) {
      u += __shfl_down(u, off, 64);
      vv += __shfl_down(vv, off, 64);
    }
    if (l == 0) { wsf[256 + o] = u; wsf[272 + o] = ((o < 6) ? b2[o] : 0.f) + vv; }
  }
  gsync(cnt, gen, 1u);

  // ---------- phase 1: x stats + t = A1*x (bf16, pixel-major) ----------
  const float* xb = x + (size_t)s * CH * HW;
  unsigned short* tb = t + (size_t)s * CH * HW;
  {
    bf16x8 af[4][2];
#pragma unroll
    for (int mf = 0; mf < 4; ++mf)
#pragma unroll
      for (int ks = 0; ks < 2; ++ks)
        af[mf][ks] = *(const bf16x8*)((const unsigned char*)a1 +
                       (mf * 16 + (l & 15)) * 128 + ks * 64 + (l >> 4) * 16);

    const int c0 = (tid >> 5) * 8;
    const int p4 = (tid & 31) * 4;
    float sacc = 0.f, qacc = 0.f;

    for (int itp = 0; itp < 8; ++itp) {
      const int pt = (j * 8 + itp) * 128;
      f32x4 v[8];
      const float* base = xb + (size_t)c0 * HW + pt + p4;
#pragma unroll
      for (int i = 0; i < 8; ++i) v[i] = *(const f32x4*)(base + (size_t)i * HW);
#pragma unroll
      for (int i = 0; i < 8; ++i)
#pragma unroll
        for (int dp = 0; dp < 4; ++dp) { float f = v[i][dp]; sacc += f; qacc += f * f; }

      __syncthreads();  // protect previous iter's LDS reads
#pragma unroll
      for (int dp = 0; dp < 4; ++dp) {
        int p = p4 + dp;
        short8 w8;
#pragma unroll
        for (int i = 0; i < 8; ++i) w8[i] = (short)f2bf(v[i][dp]);
        *(short8*)(tile + p * 128 + swz(p, c0 >> 3) * 16) = w8;
      }
      __syncthreads();

#pragma unroll
      for (int nf = 0; nf < 2; ++nf) {
        const int pl = w * 32 + nf * 16 + (l & 15);
        bf16x8 bfr[2];
#pragma unroll
        for (int ks = 0; ks < 2; ++ks) {
          int cc = ks * 4 + (l >> 4);
          bfr[ks] = *(const bf16x8*)(tile + pl * 128 + swz(pl, cc) * 16);
        }
#pragma unroll
        for (int mf = 0; mf < 4; ++mf) {
          f32x4 acc = {0.f, 0.f, 0.f, 0.f};
          acc = __builtin_amdgcn_mfma_f32_16x16x32_bf16(af[mf][0], bfr[0], acc, 0, 0, 0);
          acc = __builtin_amdgcn_mfma_f32_16x16x32_bf16(af[mf][1], bfr[1], acc, 0, 0, 0);
          short4v sv;
#pragma unroll
          for (int r = 0; r < 4; ++r) sv[r] = (short)f2bf(acc[r]);
          int o0 = mf * 16 + (l >> 4) * 4;
          *(short4v*)(tb + (size_t)(pt + pl) * CH + o0) = sv;
        }
      }
    }

#pragma unroll
    for (int off = 32; off > 0; off >>= 1) {
      sacc += __shfl_down(sacc, off, 64);
      qacc += __shfl_down(qacc, off, 64);
    }
    if (l == 0) { red[w] = sacc; red[4 + w] = qacc; }
    __syncthreads();
    if (tid == 0) {
      atomicAdd(wsf + 16 + s, red[0] + red[1] + red[2] + red[3]);
      atomicAdd(wsf + 32 + s, red[4] + red[5] + red[6] + red[7]);
    }
  }
  gsync(cnt, gen, 2u);

  // ---------- phase 2: h = silu(rs1*t + c1) stats ----------
  {
    const float m1 = wsf[16 + s] / NPIXF;
    const float rs1 = rsqrtf(wsf[32 + s] / NPIXF - m1 * m1 + 1e-6f);
    if (tid < 64) c1s[tid] = wsf[192 + tid] - rs1 * m1 * wsf[128 + tid];
    __syncthreads();
    const int cc0 = (tid & 7) * 8;
    float hs = 0.f, hq = 0.f;
    for (int it2 = 0; it2 < 32; ++it2) {
      int u = j * 8192 + it2 * 256 + tid;
      short8 tv = *(const short8*)(tb + (size_t)u * 8);
#pragma unroll
      for (int i = 0; i < 8; ++i) {
        float z = rs1 * bf2f((unsigned short)tv[i]) + c1s[cc0 + i];
        float hh = z / (1.f + __expf(-z));
        hs += hh; hq += hh * hh;
      }
    }
#pragma unroll
    for (int off = 32; off > 0; off >>= 1) {
      hs += __shfl_down(hs, off, 64);
      hq += __shfl_down(hq, off, 64);
    }
    if (l == 0) { red[w] = hs; red[4 + w] = hq; }
    __syncthreads();
    if (tid == 0) {
      atomicAdd(wsf + 48 + s, red[0] + red[1] + red[2] + red[3]);
      atomicAdd(wsf + 64 + s, red[4] + red[5] + red[6] + red[7]);
    }
  }
  gsync(cnt, gen, 3u);

  // ---------- phase 3: out = rs2*(A2*silu(rs1*t+c1)) + c2 ----------
  {
    const float m1 = wsf[16 + s] / NPIXF;
    const float rs1 = rsqrtf(wsf[32 + s] / NPIXF - m1 * m1 + 1e-6f);
    const float m2 = wsf[48 + s] / NPIXF;
    const float rs2 = rsqrtf(wsf[64 + s] / NPIXF - m2 * m2 + 1e-6f);
    // c1s still valid in LDS from phase 2 (same block, same sample)
    if (tid >= 64 && tid < 72) {
      int o = tid - 64;
      c2s[o] = (o < 6) ? (wsf[272 + o] - rs2 * m2 * wsf[256 + o]) : 0.f;
    }
    __syncthreads();
    bf16x8 a2f[2];
#pragma unroll
    for (int ks = 0; ks < 2; ++ks)
      a2f[ks] = *(const bf16x8*)((const unsigned char*)a2 +
                   (l & 15) * 128 + ks * 64 + (l >> 4) * 16);
    float* ob = out + (size_t)s * 6 * HW;
    for (int itp = 0; itp < 8; ++itp) {
      const int pt = (j * 8 + itp) * 128;
#pragma unroll
      for (int nf = 0; nf < 2; ++nf) {
        const int p = pt + w * 32 + nf * 16 + (l & 15);
        f32x4 acc = {0.f, 0.f, 0.f, 0.f};
#pragma unroll
        for (int ks = 0; ks < 2; ++ks) {
          const int ccc = ks * 32 + (l >> 4) * 8;
          short8 tv = *(const short8*)(tb + (size_t)p * CH + ccc);
          short8 hsv;
#pragma unroll
          for (int i = 0; i < 8; ++i) {
            float z = rs1 * bf2f((unsigned short)tv[i]) + c1s[ccc + i];
            float hh = z / (1.f + __expf(-z));
            hsv[i] = (short)f2bf(hh);
          }
          acc = __builtin_amdgcn_mfma_f32_16x16x32_bf16(a2f[ks], __builtin_bit_cast(bf16x8, hsv), acc, 0, 0, 0);
        }
        const int ob0 = (l >> 4) * 4;
#pragma unroll
        for (int r = 0; r < 4; ++r) {
          int o = ob0 + r;
          if (o < 6) ob[(size_t)o * HW + p] = rs2 * acc[r] + c2s[o];
        }
      }
    }
  }
}

extern "C" void kernel_launch(void* const* d_in, const int* in_sizes, int n_in,
                              void* d_out, int out_size, void* d_ws, size_t ws_size,
                              hipStream_t stream) {
  const float* x  = (const float*)d_in[0];
  const float* s1 = (const float*)d_in[1];
  const float* g1 = (const float*)d_in[2];
  const float* w1 = (const float*)d_in[3];
  const float* b1 = (const float*)d_in[4];
  const float* s2 = (const float*)d_in[5];
  const float* g2 = (const float*)d_in[6];
  const float* w2 = (const float*)d_in[7];
  const float* b2 = (const float*)d_in[8];
  float* out = (float*)d_out;

  const size_t need = 16384u + (size_t)16 * CH * HW * sizeof(unsigned short);
  if (ws_size < need) return;

  hipMemsetAsync(d_ws, 0, 512, stream);  // barrier state + stat accumulators
  fused<<<dim3(NBLK), dim3(256), 0, stream>>>(x, s1, g1, w1, b1, s2, g2, w2, b2,
                                              (unsigned char*)d_ws, out);
}

// Round 3
// 259.698 us; speedup vs baseline: 3.1448x; 3.1448x over previous
//
#include <hip/hip_runtime.h>

#define HW 65536
#define CH 64
#define NPIXF 4194304.0f

typedef __attribute__((ext_vector_type(8))) short short8;
typedef __attribute__((ext_vector_type(4))) short short4v;
typedef __attribute__((ext_vector_type(8))) __bf16 bf16x8;
typedef __attribute__((ext_vector_type(4))) float f32x4;

__device__ __forceinline__ unsigned short f2bf(float f) {
  unsigned int u = __builtin_bit_cast(unsigned int, f);
  u += 0x7FFFu + ((u >> 16) & 1u);
  return (unsigned short)(u >> 16);
}
__device__ __forceinline__ float bf2f(unsigned short h) {
  return __builtin_bit_cast(float, ((unsigned int)h) << 16);
}
__device__ __forceinline__ int swz(int p, int cc) { return cc ^ ((p ^ (p >> 3)) & 7); }

// ws float layout: [16..31]=sum_x [32..47]=sumsq_x [48..63]=sum_h [64..79]=sumsq_h
//                  [128..191]=u1  [192..255]=v1    [256..271]=u2  [272..287]=v2
// bytes: a1 bf16[64][64] @2048, a2 bf16[16][64] @10240, t bf16[16][HW][64] @16384

// ---- k_pre: weight prep + zero stat accumulators (1 block, 256 thr) ----
__global__ __launch_bounds__(256) void k_pre(
    const float* __restrict__ w1, const float* __restrict__ b1,
    const float* __restrict__ s1, const float* __restrict__ gb1,
    const float* __restrict__ w2, const float* __restrict__ b2,
    const float* __restrict__ s2, const float* __restrict__ gb2,
    float* __restrict__ wsf,
    unsigned short* __restrict__ a1, unsigned short* __restrict__ a2) {
  const int tid = threadIdx.x;
  // a1: thread = (row o1 = tid>>2, quarter q = tid&3)
  {
    int o = tid >> 2, q = tid & 3;
    float u = 0.f, v = 0.f;
    unsigned short loc[16];
#pragma unroll
    for (int i = 0; i < 16; ++i) {
      int c = q * 16 + i;
      float w = w1[o * 64 + c];
      float wsc = w * s1[c];
      loc[i] = f2bf(wsc);
      u += wsc;
      v += w * gb1[c];
    }
    *(short8*)(a1 + o * 64 + q * 16) = *(short8*)loc;
    *(short8*)(a1 + o * 64 + q * 16 + 8) = *(short8*)(loc + 8);
    u += __shfl_xor(u, 1, 64); u += __shfl_xor(u, 2, 64);
    v += __shfl_xor(v, 1, 64); v += __shfl_xor(v, 2, 64);
    if (q == 0) { wsf[128 + o] = u; wsf[192 + o] = b1[o] + v; }
  }
  // a2: threads 0..63 = (row o = tid>>2 in 0..15, quarter q)
  if (tid < 64) {
    int o = tid >> 2, q = tid & 3;
    float u = 0.f, v = 0.f;
    unsigned short loc[16];
#pragma unroll
    for (int i = 0; i < 16; ++i) {
      int c = q * 16 + i;
      float w = (o < 6) ? w2[o * 64 + c] : 0.f;
      float wsc = w * s2[c];
      loc[i] = f2bf(wsc);
      u += wsc;
      v += w * gb2[c];
    }
    *(short8*)(a2 + o * 64 + q * 16) = *(short8*)loc;
    *(short8*)(a2 + o * 64 + q * 16 + 8) = *(short8*)(loc + 8);
    u += __shfl_xor(u, 1, 64); u += __shfl_xor(u, 2, 64);
    v += __shfl_xor(v, 1, 64); v += __shfl_xor(v, 2, 64);
    if (q == 0) { wsf[256 + o] = u; wsf[272 + o] = ((o < 6) ? b2[o] : 0.f) + v; }
  }
  if (tid >= 192) wsf[16 + (tid - 192)] = 0.f;  // zero 64 stat slots
}

// ---- k1: x stats + t = A1*x (bf16, pixel-major [p][c]) ----
__global__ __launch_bounds__(256) void k1(const float* __restrict__ x,
                                          const unsigned short* __restrict__ a1,
                                          float* __restrict__ wsf,
                                          unsigned short* __restrict__ t) {
  __shared__ __align__(16) unsigned char tile[128 * 128];
  __shared__ float red[8];
  const int tid = threadIdx.x;
  const int l = tid & 63, w = tid >> 6;
  const int b = blockIdx.y;
  const int ptile = blockIdx.x * 128;
  const float* xb = x + (size_t)b * CH * HW;

  bf16x8 af[4][2];
#pragma unroll
  for (int mf = 0; mf < 4; ++mf)
#pragma unroll
    for (int ks = 0; ks < 2; ++ks)
      af[mf][ks] = *(const bf16x8*)((const unsigned char*)a1 +
                     (mf * 16 + (l & 15)) * 128 + ks * 64 + (l >> 4) * 16);

  const int c0 = (tid >> 5) * 8;
  const int p4 = (tid & 31) * 4;
  f32x4 v[8];
  const float* base = xb + (size_t)c0 * HW + ptile + p4;
#pragma unroll
  for (int i = 0; i < 8; ++i) v[i] = *(const f32x4*)(base + (size_t)i * HW);

  float s = 0.f, q = 0.f;
#pragma unroll
  for (int i = 0; i < 8; ++i)
#pragma unroll
    for (int dp = 0; dp < 4; ++dp) { float f = v[i][dp]; s += f; q += f * f; }
#pragma unroll
  for (int off = 32; off > 0; off >>= 1) {
    s += __shfl_down(s, off, 64);
    q += __shfl_down(q, off, 64);
  }
  if (l == 0) { red[w] = s; red[4 + w] = q; }

#pragma unroll
  for (int dp = 0; dp < 4; ++dp) {
    int p = p4 + dp;
    short8 w8;
#pragma unroll
    for (int i = 0; i < 8; ++i) w8[i] = (short)f2bf(v[i][dp]);
    *(short8*)(tile + p * 128 + swz(p, c0 >> 3) * 16) = w8;
  }
  __syncthreads();

  unsigned short* tb = t + (size_t)b * CH * HW;
#pragma unroll
  for (int nf = 0; nf < 2; ++nf) {
    const int pl = w * 32 + nf * 16 + (l & 15);
    bf16x8 bfr[2];
#pragma unroll
    for (int ks = 0; ks < 2; ++ks) {
      int cc = ks * 4 + (l >> 4);
      bfr[ks] = *(const bf16x8*)(tile + pl * 128 + swz(pl, cc) * 16);
    }
#pragma unroll
    for (int mf = 0; mf < 4; ++mf) {
      f32x4 acc = {0.f, 0.f, 0.f, 0.f};
      acc = __builtin_amdgcn_mfma_f32_16x16x32_bf16(af[mf][0], bfr[0], acc, 0, 0, 0);
      acc = __builtin_amdgcn_mfma_f32_16x16x32_bf16(af[mf][1], bfr[1], acc, 0, 0, 0);
      short4v sv;
#pragma unroll
      for (int r = 0; r < 4; ++r) sv[r] = (short)f2bf(acc[r]);
      int o0 = mf * 16 + (l >> 4) * 4;
      *(short4v*)(tb + (size_t)(ptile + pl) * CH + o0) = sv;
    }
  }

  if (tid == 0) {
    atomicAdd(wsf + 16 + b, red[0] + red[1] + red[2] + red[3]);
    atomicAdd(wsf + 32 + b, red[4] + red[5] + red[6] + red[7]);
  }
}

// ---- k2: h = silu(rs1*t + c1); h stats; y = A2*h -> d_out (raw, no rs2) ----
__global__ __launch_bounds__(256) void k2(const unsigned short* __restrict__ t,
                                          const unsigned short* __restrict__ a2,
                                          float* __restrict__ wsf,
                                          float* __restrict__ out) {
  __shared__ float c1s[64];
  __shared__ float red[8];
  const int tid = threadIdx.x;
  const int l = tid & 63, w = tid >> 6;
  const int s = blockIdx.y;
  const int ptile = blockIdx.x * 128;
  const float m1 = wsf[16 + s] / NPIXF;
  const float rs1 = rsqrtf(wsf[32 + s] / NPIXF - m1 * m1 + 1e-6f);
  if (tid < 64) c1s[tid] = wsf[192 + tid] - rs1 * m1 * wsf[128 + tid];
  __syncthreads();

  bf16x8 a2f[2];
#pragma unroll
  for (int ks = 0; ks < 2; ++ks)
    a2f[ks] = *(const bf16x8*)((const unsigned char*)a2 +
                 (l & 15) * 128 + ks * 64 + (l >> 4) * 16);

  const unsigned short* tb = t + (size_t)s * CH * HW;
  float* ob = out + (size_t)s * 6 * HW;
  float hs = 0.f, hq = 0.f;
#pragma unroll
  for (int nf = 0; nf < 2; ++nf) {
    const int p = ptile + w * 32 + nf * 16 + (l & 15);
    f32x4 acc = {0.f, 0.f, 0.f, 0.f};
#pragma unroll
    for (int ks = 0; ks < 2; ++ks) {
      const int ccc = ks * 32 + (l >> 4) * 8;
      short8 tv = *(const short8*)(tb + (size_t)p * CH + ccc);
      short8 hsv;
#pragma unroll
      for (int i = 0; i < 8; ++i) {
        float z = rs1 * bf2f((unsigned short)tv[i]) + c1s[ccc + i];
        float hh = z / (1.f + __expf(-z));
        hs += hh; hq += hh * hh;
        hsv[i] = (short)f2bf(hh);
      }
      acc = __builtin_amdgcn_mfma_f32_16x16x32_bf16(a2f[ks], __builtin_bit_cast(bf16x8, hsv), acc, 0, 0, 0);
    }
    const int ob0 = (l >> 4) * 4;
#pragma unroll
    for (int r = 0; r < 4; ++r) {
      int o = ob0 + r;
      if (o < 6) ob[(size_t)o * HW + p] = acc[r];  // raw y, rescaled in k3
    }
  }

#pragma unroll
  for (int off = 32; off > 0; off >>= 1) {
    hs += __shfl_down(hs, off, 64);
    hq += __shfl_down(hq, off, 64);
  }
  if (l == 0) { red[w] = hs; red[4 + w] = hq; }
  __syncthreads();
  if (tid == 0) {
    atomicAdd(wsf + 48 + s, red[0] + red[1] + red[2] + red[3]);
    atomicAdd(wsf + 64 + s, red[4] + red[5] + red[6] + red[7]);
  }
}

// ---- k3: out = rs2*out + c2[o]  (in-place, elementwise) ----
__global__ __launch_bounds__(256) void k3(float* __restrict__ out,
                                          const float* __restrict__ wsf) {
  const int s = blockIdx.y;
  const float m2 = wsf[48 + s] / NPIXF;
  const float rs2 = rsqrtf(wsf[64 + s] / NPIXF - m2 * m2 + 1e-6f);
  float* ob = out + (size_t)s * 6 * HW;
#pragma unroll
  for (int it = 0; it < 4; ++it) {
    int f4 = blockIdx.x * 256 + threadIdx.x + it * 24576;  // < 98304
    int o = f4 >> 14;  // 16384 f32x4 per output channel
    float c2 = wsf[272 + o] - rs2 * m2 * wsf[256 + o];
    f32x4* p = (f32x4*)ob + f4;
    f32x4 v = *p;
#pragma unroll
    for (int i = 0; i < 4; ++i) v[i] = rs2 * v[i] + c2;
    *p = v;
  }
}

extern "C" void kernel_launch(void* const* d_in, const int* in_sizes, int n_in,
                              void* d_out, int out_size, void* d_ws, size_t ws_size,
                              hipStream_t stream) {
  const float* x  = (const float*)d_in[0];
  const float* s1 = (const float*)d_in[1];
  const float* g1 = (const float*)d_in[2];
  const float* w1 = (const float*)d_in[3];
  const float* b1 = (const float*)d_in[4];
  const float* s2 = (const float*)d_in[5];
  const float* g2 = (const float*)d_in[6];
  const float* w2 = (const float*)d_in[7];
  const float* b2 = (const float*)d_in[8];
  float* out = (float*)d_out;
  float* wsf = (float*)d_ws;
  unsigned short* a1 = (unsigned short*)((char*)d_ws + 2048);
  unsigned short* a2 = (unsigned short*)((char*)d_ws + 10240);
  unsigned short* t  = (unsigned short*)((char*)d_ws + 16384);

  const size_t need = 16384u + (size_t)16 * CH * HW * sizeof(unsigned short);
  if (ws_size < need) return;

  k_pre<<<1, 256, 0, stream>>>(w1, b1, s1, g1, w2, b2, s2, g2, wsf, a1, a2);
  k1<<<dim3(512, 16), 256, 0, stream>>>(x, a1, wsf, t);
  k2<<<dim3(512, 16), 256, 0, stream>>>(t, a2, wsf, out);
  k3<<<dim3(96, 16), 256, 0, stream>>>(out, wsf);
}